// Round 1
// baseline (190.529 us; speedup 1.0000x reference)
//
#include <hip/hip_runtime.h>

#define TT 1024
#define BB 32
#define KKD 8
#define NN 64
#define MM 64
#define BKC (BB*KKD)     // 256
#define KN  (KKD*NN)     // 512
// ws layout (bytes):
//   0        : Bp   (K*N*2 f32)            = 4096
//   4096     : W1   (1024*64 f32)          = 262144
//   266240   : W2   (1024*64 f32)          = 262144
//   528384   : state(B*K*N*6 f32)          = 393216
//   921600   : s3buf(chunkT*B*K*N*2 f32)   = chunkT*131072

__global__ __launch_bounds__(64) void bp_kernel(const float* __restrict__ lam_re,
                                                const float* __restrict__ lam_im,
                                                float* __restrict__ bp) {
    int k = blockIdx.x;      // 0..7
    int j = threadIdx.x;     // 0..63
    double ljre = (double)lam_re[k*NN+j], ljim = (double)lam_im[k*NN+j];
    double dj = ljre*ljre + ljim*ljim;
    double pre = 1.0, pim = 0.0;
    for (int i = 0; i < NN; ++i) {
        if (i == j) continue;
        double lire = (double)lam_re[k*NN+i], liim = (double)lam_im[k*NN+i];
        double rre = (lire*ljre + liim*ljim)/dj;
        double rim = (liim*ljre - lire*ljim)/dj;
        double zre = 1.0 - rre, zim = -rim;      // z = 1 - lam_i/lam_j
        double zd = zre*zre + zim*zim;
        double npre = (pre*zre + pim*zim)/zd;    // p /= z
        double npim = (pim*zre - pre*zim)/zd;
        pre = npre; pim = npim;
    }
    bp[(k*NN+j)*2+0] = (float)pre;
    bp[(k*NN+j)*2+1] = (float)pim;
}

// W1[(2*(k*N+n)+p)][m]: p=0 -> Cre/K, p=1 -> -Cim/K   (real part of C's)
// W2:                   p=0 -> Cim/K, p=1 ->  Cre/K   (imag part, hedge)
__global__ __launch_bounds__(256) void wprep_kernel(const float* __restrict__ C_re,
                                                    const float* __restrict__ C_im,
                                                    float* __restrict__ W1,
                                                    float* __restrict__ W2) {
    int idx = blockIdx.x*256 + threadIdx.x;   // 0..65535
    int j = idx >> 6;       // A-column 0..1023
    int m = idx & 63;
    int kn = j >> 1;
    int p = j & 1;
    float cre = C_re[kn*MM + m] * 0.125f;
    float cim = C_im[kn*MM + m] * 0.125f;
    W1[idx] = p ? -cim : cre;
    W2[idx] = p ?  cre : cim;
}

// Fused 3-pass scan. One wave per (b,k); lane = n. Writes s3 (pre-update,
// i.e. the shifted state the reference uses) for every t.
__global__ __launch_bounds__(64) void scan_kernel(const float* __restrict__ x,
                                                  const float* __restrict__ lam_re,
                                                  const float* __restrict__ lam_im,
                                                  const float* __restrict__ bp,
                                                  float* __restrict__ state,
                                                  float2* __restrict__ s3buf,
                                                  int chunk_start, int chunk_len) {
    int bk = blockIdx.x;        // 0..255
    int b = bk >> 3;
    int k = bk & 7;
    int n = threadIdx.x;        // 0..63
    int kn = k*NN + n;
    float lre = lam_re[kn], lim = lam_im[kn];
    float bpre = bp[2*kn+0], bpim = bp[2*kn+1];
    float l2 = lre*lre + lim*lim;
    int chain = bk*NN + n;

    float s1re,s1im,s2re,s2im,s3re,s3im;
    if (chunk_start == 0) {
        s1re=s1im=s2re=s2im=s3re=s3im=0.f;
    } else {
        const float* st = state + (size_t)chain*6;
        s1re=st[0];s1im=st[1];s2re=st[2];s2im=st[3];s3re=st[4];s3im=st[5];
    }

    const float* xp = x + b*KKD + k;                 // + t*BKC
    float2* os = s3buf + (size_t)b*KN + kn;          // + lt*(BB*KN)

    for (int t0 = 0; t0 < chunk_len; t0 += 64) {
        // stage 64 timesteps of x across the wave
        float xs = xp[(size_t)(chunk_start + t0 + n) * BKC];
        #pragma unroll 4
        for (int j = 0; j < 64; ++j) {
            os[(size_t)(t0 + j) * (BB*KN)] = make_float2(s3re, s3im);
            float xv = __shfl(xs, j, 64);
            float ure = xv * bpre, uim = xv * bpim;
            // alphas from PREVIOUS states (t-1), |lam*s|^2 = |lam|^2 |s|^2
            float a1 = rsqrtf(1.f + l2*(s1re*s1re + s1im*s1im));
            float a2 = rsqrtf(1.f + l2*(s2re*s2re + s2im*s2im));
            // s1 = lam*s1 + u
            float t1re = lre*s1re - lim*s1im + ure;
            float t1im = lre*s1im + lim*s1re + uim;
            s1re=t1re; s1im=t1im;
            // s2 = a1*lam*s2 + u
            float p2re = a1*s2re, p2im = a1*s2im;
            float t2re = lre*p2re - lim*p2im + ure;
            float t2im = lre*p2im + lim*p2re + uim;
            s2re=t2re; s2im=t2im;
            // s3 = a2*lam*s3 + u
            float p3re = a2*s3re, p3im = a2*s3im;
            float t3re = lre*p3re - lim*p3im + ure;
            float t3im = lre*p3im + lim*p3re + uim;
            s3re=t3re; s3im=t3im;
        }
    }
    float* st = state + (size_t)chain*6;
    st[0]=s1re;st[1]=s1im;st[2]=s2re;st[3]=s2im;st[4]=s3re;st[5]=s3im;
}

// out(t,b,m) = dot(A_row(t,b), W1[:,m]) + (x(t,b,:)·D(:,m) + sum_k Do[k,m])/K
template<bool CPLX>
__global__ __launch_bounds__(256) void proj_kernel(const float* __restrict__ A,
                                                   const float* __restrict__ W1,
                                                   const float* __restrict__ W2,
                                                   const float* __restrict__ x,
                                                   const float* __restrict__ D,
                                                   const float* __restrict__ Do,
                                                   float* __restrict__ out,
                                                   int chunk_start) {
    __shared__ float As[64][68];                 // transposed: As[kk][row]
    __shared__ float Ws[64][64];
    __shared__ float Ws2[CPLX ? 64 : 1][64];
    __shared__ float Ds[8][64];
    __shared__ float Dob[64];

    int tid = threadIdx.x;
    if (tid < 64) {
        float s = 0.f;
        #pragma unroll
        for (int k = 0; k < 8; ++k) { Ds[k][tid] = D[k*64+tid]; s += Do[k*64+tid]; }
        Dob[tid] = s;
    }
    int trow = tid >> 4, tcol = tid & 15;
    float acc[4][4] = {};
    float acc2[4][4] = {};

    const float* Arow = A + (size_t)blockIdx.x*64*1024;

    for (int kt = 0; kt < 16; ++kt) {
        #pragma unroll
        for (int p = 0; p < 4; ++p) {
            int idx = p*1024 + tid*4;
            int r = idx >> 6, c = idx & 63;
            float4 v = *(const float4*)(Arow + (size_t)r*1024 + kt*64 + c);
            As[c+0][r]=v.x; As[c+1][r]=v.y; As[c+2][r]=v.z; As[c+3][r]=v.w;
        }
        #pragma unroll
        for (int p = 0; p < 4; ++p) {
            ((float4*)Ws)[p*256 + tid] = ((const float4*)(W1 + kt*4096))[p*256 + tid];
            if (CPLX)
                ((float4*)Ws2)[p*256 + tid] = ((const float4*)(W2 + kt*4096))[p*256 + tid];
        }
        __syncthreads();
        #pragma unroll 8
        for (int kk = 0; kk < 64; ++kk) {
            float4 av = *(const float4*)&As[kk][trow*4];
            float4 wv = *(const float4*)&Ws[kk][tcol*4];
            float a_[4] = {av.x, av.y, av.z, av.w};
            float w_[4] = {wv.x, wv.y, wv.z, wv.w};
            #pragma unroll
            for (int i = 0; i < 4; ++i)
                #pragma unroll
                for (int j2 = 0; j2 < 4; ++j2)
                    acc[i][j2] += a_[i]*w_[j2];
            if (CPLX) {
                float4 w2 = *(const float4*)&Ws2[kk][tcol*4];
                float w2_[4] = {w2.x, w2.y, w2.z, w2.w};
                #pragma unroll
                for (int i = 0; i < 4; ++i)
                    #pragma unroll
                    for (int j2 = 0; j2 < 4; ++j2)
                        acc2[i][j2] += a_[i]*w2_[j2];
            }
        }
        __syncthreads();
    }

    int rowInChunk = blockIdx.x*64 + trow*4;
    #pragma unroll
    for (int i = 0; i < 4; ++i) {
        size_t grow = (size_t)chunk_start*BB + rowInChunk + i;   // = t*B + b
        const float* xr = x + grow*8;
        float xk[8];
        #pragma unroll
        for (int k = 0; k < 8; ++k) xk[k] = xr[k];
        #pragma unroll
        for (int j2 = 0; j2 < 4; ++j2) {
            int m = tcol*4 + j2;
            float xd = 0.f;
            #pragma unroll
            for (int k = 0; k < 8; ++k) xd += xk[k]*Ds[k][m];
            float val = acc[i][j2] + 0.125f*(xd + Dob[m]);
            if (!CPLX) {
                out[grow*64 + m] = val;
            } else {
                out[(grow*64 + m)*2 + 0] = val;
                out[(grow*64 + m)*2 + 1] = acc2[i][j2];
            }
        }
    }
}

extern "C" void kernel_launch(void* const* d_in, const int* in_sizes, int n_in,
                              void* d_out, int out_size, void* d_ws, size_t ws_size,
                              hipStream_t stream) {
    const float* x      = (const float*)d_in[0];
    const float* lam_re = (const float*)d_in[1];
    const float* lam_im = (const float*)d_in[2];
    const float* C_re   = (const float*)d_in[3];
    const float* C_im   = (const float*)d_in[4];
    const float* D      = (const float*)d_in[5];
    const float* Do     = (const float*)d_in[6];
    float* out = (float*)d_out;

    char* ws = (char*)d_ws;
    float*  bpw   = (float*)(ws);
    float*  W1    = (float*)(ws + 4096);
    float*  W2    = (float*)(ws + 266240);
    float*  statew= (float*)(ws + 528384);
    float*  s3w   = (float*)(ws + 921600);

    const size_t base = 921600;
    const size_t perT = (size_t)BB*KN*2*4;   // 131072 B per timestep
    int chunkT = TT;
    if (ws_size < base + (size_t)TT*perT) {
        size_t avail = ws_size > base ? ws_size - base : 0;
        chunkT = (int)(avail / perT) & ~63;
        if (chunkT < 64) chunkT = 64;        // minimum granularity
    }

    bp_kernel<<<KKD, NN, 0, stream>>>(lam_re, lam_im, bpw);
    wprep_kernel<<<256, 256, 0, stream>>>(C_re, C_im, W1, W2);

    bool cplx = (out_size == TT*BB*MM*2);
    for (int cs = 0; cs < TT; cs += chunkT) {
        int len = (chunkT < TT - cs) ? chunkT : (TT - cs);
        scan_kernel<<<BKC, NN, 0, stream>>>(x, lam_re, lam_im, bpw, statew,
                                            (float2*)s3w, cs, len);
        int nrow = len * BB;
        if (cplx)
            proj_kernel<true ><<<nrow/64, 256, 0, stream>>>(s3w, W1, W2, x, D, Do, out, cs);
        else
            proj_kernel<false><<<nrow/64, 256, 0, stream>>>(s3w, W1, W2, x, D, Do, out, cs);
    }
}

// Round 2
// 129.725 us; speedup vs baseline: 1.4687x; 1.4687x over previous
//
#include <hip/hip_runtime.h>

#define TT 1024
#define BB 32
#define KKD 8
#define NN 64
#define MM 64
#define BKC (BB*KKD)     // 256
#define KN  (KKD*NN)     // 512

typedef __attribute__((ext_vector_type(8))) _Float16 f16x8;
typedef __attribute__((ext_vector_type(4))) float f32x4;

#define SC_DOWN (1.0f/4096.0f)   // scale applied to s3 before f16 store
#define SC_UP   512.0f           // 4096 * (1/8 k-mean) applied to W

// ws layout (bytes):
//   0       : Bp   (K*N*2 f32)           = 4096
//   4096    : Wt   (64*1024 f16)         = 131072   -> ends 135168
//   135168  : state(B*K*N*6 f32)         = 393216   -> ends 528384
//   528384  : abuf (chunkT*B*K*N f16x2)  = chunkT*65536

static __device__ __forceinline__ float bcast(float v, int lane) {
    return __builtin_bit_cast(float,
        __builtin_amdgcn_readlane(__builtin_bit_cast(int, v), lane));
}

__global__ __launch_bounds__(64) void bp_kernel(const float* __restrict__ lam_re,
                                                const float* __restrict__ lam_im,
                                                float* __restrict__ bp) {
    int k = blockIdx.x;      // 0..7
    int j = threadIdx.x;     // 0..63
    double ljre = (double)lam_re[k*NN+j], ljim = (double)lam_im[k*NN+j];
    double dj = ljre*ljre + ljim*ljim;
    double pre = 1.0, pim = 0.0;
    for (int i = 0; i < NN; ++i) {
        if (i == j) continue;
        double lire = (double)lam_re[k*NN+i], liim = (double)lam_im[k*NN+i];
        double rre = (lire*ljre + liim*ljim)/dj;
        double rim = (liim*ljre - lire*ljim)/dj;
        double zre = 1.0 - rre, zim = -rim;      // z = 1 - lam_i/lam_j
        double zd = zre*zre + zim*zim;
        double npre = (pre*zre + pim*zim)/zd;    // p /= z
        double npim = (pim*zre - pre*zim)/zd;
        pre = npre; pim = npim;
    }
    bp[(k*NN+j)*2+0] = (float)pre;
    bp[(k*NN+j)*2+1] = (float)pim;
}

// Wt[m][j] (64 x 1024 f16): j=2*kn+p; p=0 -> Cre*512, p=1 -> -Cim*512
__global__ __launch_bounds__(256) void wprep_kernel(const float* __restrict__ C_re,
                                                    const float* __restrict__ C_im,
                                                    unsigned short* __restrict__ Wt) {
    int idx = blockIdx.x*256 + threadIdx.x;   // 0..65535
    int m  = idx >> 10;
    int j  = idx & 1023;
    int kn = j >> 1;
    float v = (j & 1) ? -C_im[kn*MM + m] : C_re[kn*MM + m];
    Wt[idx] = __builtin_bit_cast(unsigned short, (_Float16)(v * SC_UP));
}

// Fused 3-pass scan, window-decoupled chains. One wave per (b,k); lane = n.
// Writes s3 (pre-update) as scaled f16 pairs: A[row=t*B+b][col=2kn+p].
__global__ __launch_bounds__(64) void scan_kernel(const float* __restrict__ x,
                                                  const float* __restrict__ lam_re,
                                                  const float* __restrict__ lam_im,
                                                  const float* __restrict__ bp,
                                                  float* __restrict__ state,
                                                  unsigned int* __restrict__ abuf,
                                                  int chunk_start, int chunk_len) {
    int bk = blockIdx.x;        // 0..255
    int b = bk >> 3;
    int k = bk & 7;
    int n = threadIdx.x;        // 0..63
    int kn = k*NN + n;
    float lre = lam_re[kn], lim = lam_im[kn];
    float bpre = bp[2*kn+0], bpim = bp[2*kn+1];
    float l2 = lre*lre + lim*lim;
    int chain = bk*NN + n;

    float s1re,s1im,s2re,s2im,s3re,s3im;
    if (chunk_start == 0) {
        s1re=s1im=s2re=s2im=s3re=s3im=0.f;
    } else {
        const float* st = state + (size_t)chain*6;
        s1re=st[0];s1im=st[1];s2re=st[2];s2im=st[3];s3re=st[4];s3im=st[5];
    }

    const float* xp = x + (size_t)chunk_start*BKC + b*KKD + k;
    unsigned int* ap = abuf + (size_t)b*KN + kn;   // + t*(BB*KN)

    for (int t0 = 0; t0 < chunk_len; t0 += 64) {
        float xs = xp[(size_t)(t0 + n) * BKC];     // lane n holds x at t0+n
        #pragma unroll
        for (int w = 0; w < 4; ++w) {
            float mm_[16], cre[16], cim[16];
            // ---- pass 1: plain lambda chain; tap |s1|^2 pre-update ----
            #pragma unroll
            for (int j = 0; j < 16; ++j) {
                float xv = bcast(xs, w*16 + j);
                mm_[j] = __builtin_fmaf(l2, s1re*s1re + s1im*s1im, 1.0f);
                float ure = xv*bpre, uim = xv*bpim;
                float tre = __builtin_fmaf(lre, s1re, __builtin_fmaf(-lim, s1im, ure));
                float tim = __builtin_fmaf(lre, s1im, __builtin_fmaf( lim, s1re, uim));
                s1re=tre; s1im=tim;
            }
            #pragma unroll
            for (int j = 0; j < 16; ++j) {         // batched rsqrt (off-chain)
                float a = rsqrtf(mm_[j]); cre[j] = a*lre; cim[j] = a*lim;
            }
            // ---- pass 2: coeff = alpha1*lambda; tap |s2|^2 pre-update ----
            #pragma unroll
            for (int j = 0; j < 16; ++j) {
                float xv = bcast(xs, w*16 + j);
                mm_[j] = __builtin_fmaf(l2, s2re*s2re + s2im*s2im, 1.0f);
                float ure = xv*bpre, uim = xv*bpim;
                float tre = __builtin_fmaf(cre[j], s2re, __builtin_fmaf(-cim[j], s2im, ure));
                float tim = __builtin_fmaf(cre[j], s2im, __builtin_fmaf( cim[j], s2re, uim));
                s2re=tre; s2im=tim;
            }
            #pragma unroll
            for (int j = 0; j < 16; ++j) {
                float a = rsqrtf(mm_[j]); cre[j] = a*lre; cim[j] = a*lim;
            }
            // ---- pass 3: store pre-update s3 (scaled f16), then update ----
            #pragma unroll
            for (int j = 0; j < 16; ++j) {
                unsigned short hr = __builtin_bit_cast(unsigned short, (_Float16)(s3re*SC_DOWN));
                unsigned short hi = __builtin_bit_cast(unsigned short, (_Float16)(s3im*SC_DOWN));
                ap[(size_t)(t0 + w*16 + j) * (BB*KN)] = ((unsigned int)hi << 16) | hr;
                float xv = bcast(xs, w*16 + j);
                float ure = xv*bpre, uim = xv*bpim;
                float tre = __builtin_fmaf(cre[j], s3re, __builtin_fmaf(-cim[j], s3im, ure));
                float tim = __builtin_fmaf(cre[j], s3im, __builtin_fmaf( cim[j], s3re, uim));
                s3re=tre; s3im=tim;
            }
        }
    }
    float* st = state + (size_t)chain*6;
    st[0]=s1re;st[1]=s1im;st[2]=s2re;st[3]=s2im;st[4]=s3re;st[5]=s3im;
}

// MFMA f16 projection: out[row][m] = A[row][:]·Wt[m][:] (scales cancel)
//                       + one appended K=32 mfma for (x·D + sum_k Do)/8.
// Block: 64 rows, 4 waves = 4 K-quarters; LDS fragment-space reduce.
__global__ __launch_bounds__(256) void proj_kernel(const unsigned short* __restrict__ A,
                                                   const unsigned short* __restrict__ Wt,
                                                   const float* __restrict__ x,
                                                   const float* __restrict__ D,
                                                   const float* __restrict__ Do,
                                                   float* __restrict__ out,
                                                   int rowOff) {
    __shared__ f32x4 red[4*4*64*4];     // [rg][wave][lane][granule^xor] = 64 KiB
    int tid = threadIdx.x;
    int w = tid >> 6, l = tid & 63;
    int lg = l >> 4, lr = l & 15;
    int R0 = blockIdx.x * 64;

    f32x4 acc[4][4];
    #pragma unroll
    for (int r = 0; r < 4; ++r)
        #pragma unroll
        for (int t = 0; t < 4; ++t) acc[r][t] = (f32x4){0.f,0.f,0.f,0.f};

    const unsigned short* Ab = A  + (size_t)(R0 + lr)*1024 + w*256 + lg*8;
    const unsigned short* Bb = Wt + (size_t)lr*1024       + w*256 + lg*8;

    #pragma unroll 2
    for (int ks = 0; ks < 8; ++ks) {
        f16x8 bf[4], af[4];
        #pragma unroll
        for (int t = 0; t < 4; ++t)
            bf[t] = __builtin_bit_cast(f16x8, *(const uint4*)(Bb + t*16*1024 + ks*32));
        #pragma unroll
        for (int r = 0; r < 4; ++r)
            af[r] = __builtin_bit_cast(f16x8, *(const uint4*)(Ab + r*16*1024 + ks*32));
        #pragma unroll
        for (int r = 0; r < 4; ++r)
            #pragma unroll
            for (int t = 0; t < 4; ++t)
                acc[r][t] = __builtin_amdgcn_mfma_f32_16x16x32_f16(af[r], bf[t], acc[r][t], 0,0,0);
    }

    // fragment-space reduce across the 4 K-quarters; wave w takes rg=w
    #pragma unroll
    for (int r = 0; r < 4; ++r)
        #pragma unroll
        for (int t = 0; t < 4; ++t)
            red[((r*4 + w)*64 + l)*4 + (t ^ (l & 3))] = acc[r][t];
    __syncthreads();

    f32x4 r2[4];
    #pragma unroll
    for (int t = 0; t < 4; ++t) r2[t] = (f32x4){0.f,0.f,0.f,0.f};
    #pragma unroll
    for (int ws_ = 0; ws_ < 4; ++ws_)
        #pragma unroll
        for (int t = 0; t < 4; ++t)
            r2[t] += red[((w*4 + ws_)*64 + l)*4 + (t ^ (l & 3))];

    // appended K=32 mfma: k'=0..7 -> x[row][k']*D[k'][m]/8 ; k'=8 -> 1*Dob[m]/8
    int rowA = rowOff + R0 + w*16 + lr;         // A-side row = lane&15
    const float* xr = x + (size_t)rowA * KKD;
    float4 x0 = *(const float4*)(xr);
    float4 x1 = *(const float4*)(xr + 4);
    f16x8 a2;
    a2[0] = (lg==0) ? (_Float16)x0.x : ((lg==1) ? (_Float16)1.0f : (_Float16)0.0f);
    a2[1] = (lg==0) ? (_Float16)x0.y : (_Float16)0.0f;
    a2[2] = (lg==0) ? (_Float16)x0.z : (_Float16)0.0f;
    a2[3] = (lg==0) ? (_Float16)x0.w : (_Float16)0.0f;
    a2[4] = (lg==0) ? (_Float16)x1.x : (_Float16)0.0f;
    a2[5] = (lg==0) ? (_Float16)x1.y : (_Float16)0.0f;
    a2[6] = (lg==0) ? (_Float16)x1.z : (_Float16)0.0f;
    a2[7] = (lg==0) ? (_Float16)x1.w : (_Float16)0.0f;

    #pragma unroll
    for (int t = 0; t < 4; ++t) {
        int c = t*16 + lr;
        float dob = 0.f;
        #pragma unroll
        for (int i = 0; i < 8; ++i) dob += Do[i*64 + c];
        f16x8 b2;
        b2[0] = (lg==0) ? (_Float16)(D[0*64+c]*0.125f)
              : ((lg==1) ? (_Float16)(dob*0.125f) : (_Float16)0.0f);
        b2[1] = (lg==0) ? (_Float16)(D[1*64+c]*0.125f) : (_Float16)0.0f;
        b2[2] = (lg==0) ? (_Float16)(D[2*64+c]*0.125f) : (_Float16)0.0f;
        b2[3] = (lg==0) ? (_Float16)(D[3*64+c]*0.125f) : (_Float16)0.0f;
        b2[4] = (lg==0) ? (_Float16)(D[4*64+c]*0.125f) : (_Float16)0.0f;
        b2[5] = (lg==0) ? (_Float16)(D[5*64+c]*0.125f) : (_Float16)0.0f;
        b2[6] = (lg==0) ? (_Float16)(D[6*64+c]*0.125f) : (_Float16)0.0f;
        b2[7] = (lg==0) ? (_Float16)(D[7*64+c]*0.125f) : (_Float16)0.0f;
        r2[t] = __builtin_amdgcn_mfma_f32_16x16x32_f16(a2, b2, r2[t], 0,0,0);
    }

    // store: D-frag row = lg*4 + reg, col = lr (within 16-tile)
    #pragma unroll
    for (int t = 0; t < 4; ++t) {
        int c = t*16 + lr;
        #pragma unroll
        for (int reg = 0; reg < 4; ++reg) {
            int row = rowOff + R0 + w*16 + lg*4 + reg;
            out[(size_t)row*MM + c] = r2[t][reg];
        }
    }
}

extern "C" void kernel_launch(void* const* d_in, const int* in_sizes, int n_in,
                              void* d_out, int out_size, void* d_ws, size_t ws_size,
                              hipStream_t stream) {
    const float* x      = (const float*)d_in[0];
    const float* lam_re = (const float*)d_in[1];
    const float* lam_im = (const float*)d_in[2];
    const float* C_re   = (const float*)d_in[3];
    const float* C_im   = (const float*)d_in[4];
    const float* D      = (const float*)d_in[5];
    const float* Do     = (const float*)d_in[6];
    float* out = (float*)d_out;

    char* ws = (char*)d_ws;
    float*          bpw    = (float*)(ws);
    unsigned short* Wt     = (unsigned short*)(ws + 4096);
    float*          statew = (float*)(ws + 135168);
    unsigned int*   abuf   = (unsigned int*)(ws + 528384);

    const size_t base = 528384;
    const size_t perT = (size_t)BB*KN*4;     // 65536 B per timestep (f16 pairs)
    int chunkT = TT;
    if (ws_size < base + (size_t)TT*perT) {
        size_t avail = ws_size > base ? ws_size - base : 0;
        chunkT = (int)(avail / perT) & ~63;
        if (chunkT < 64) chunkT = 64;
    }

    bp_kernel<<<KKD, NN, 0, stream>>>(lam_re, lam_im, bpw);
    wprep_kernel<<<256, 256, 0, stream>>>(C_re, C_im, Wt);

    for (int cs = 0; cs < TT; cs += chunkT) {
        int len = (chunkT < TT - cs) ? chunkT : (TT - cs);
        scan_kernel<<<BKC, NN, 0, stream>>>(x, lam_re, lam_im, bpw, statew,
                                            abuf, cs, len);
        proj_kernel<<<len/2, 256, 0, stream>>>((const unsigned short*)abuf, Wt,
                                               x, D, Do, out, cs*BB);
    }
}